// Round 13
// baseline (120.719 us; speedup 1.0000x reference)
//
#include <hip/hip_runtime.h>

// SoftProjection: B=4, N=8192 points, M=4096 queries, F=64 features, K=16 NN.
// R15: sparse pass B. R14 (119.3us total / 57.4us main) is VALU-issue bound;
// every non-instruction-reducing change R5-R14 was neutral. Pass A already
// computes per-(lane,query) EXACT min over the lane's 64-pt set; mn[q] > t
// => that set has no survivors for q (exact skip). Live fraction ~11.7%
// (~7.5 lanes/query). Dense pass B (~960 instr/wave) is replaced by a
// compacted rescan: per query (unrolled static), wave-uniform ballot mask;
// walk 8 items/window (SALU ffs/clear on uniform mask; cndmask select tree
// for per-lane L -- no dynamic arrays => no scratch); lane (item=lane>>3,
// g=lane&7) rescans item L's group g via ds_read_b128. ~35 VALU/window,
// ~10.6 windows/wave expected => ~500 instr/wave saved. Point planes padded
// (group stride 256->260 floats, 260=4 mod 32) so sparse reads rotate banks
// (dense reads + staging use the same closed-form pad). Survivor set
// provably identical (same fmaf VAL chain; skips exact) => radix/rank/
// epilogue byte-identical to R14. LDS 80768B => 2 blocks/CU kept.
// 512 blocks x 1024 thr.

#define BB 4
#define NN 8192
#define MM 4096
#define FF 64
#define KK 16
#define CHUNK 4096
#define PCH 4160   // padded chunk: 16 groups of 256 -> 260
#define NCHUNK 2
#define QPW 4
#define QPB 32
#define SCAP 54
#define NTHR 1024
#define STG 33

__device__ __forceinline__ float min3f(float a, float b, float c) {
    float d;
    asm("v_min3_f32 %0, %1, %2, %3" : "=v"(d) : "v"(a), "v"(b), "v"(c));
    return d;
}

__global__ __launch_bounds__(256) void transpose_feat(const float* __restrict__ pf,
                                                      float* __restrict__ pfT) {
    __shared__ float tile[64][65];
    const int b = blockIdx.y;
    const int n0 = blockIdx.x * 64;
    const int t = threadIdx.x;
    const int n = t & 63, fq = t >> 6;
#pragma unroll
    for (int i = 0; i < 16; ++i) {
        int f = fq * 16 + i;
        tile[f][n] = pf[(size_t)b * FF * NN + (size_t)f * NN + n0 + n];
    }
    __syncthreads();
    const int f2 = t & 63, nq = t >> 6;
#pragma unroll
    for (int i = 0; i < 16; ++i) {
        int nn2 = nq * 16 + i;
        pfT[(size_t)b * NN * FF + (size_t)(n0 + nn2) * FF + f2] = tile[f2][nn2];
    }
}

__device__ __forceinline__ unsigned mapf(float f) {
    unsigned u = __float_as_uint(f);
    return (u & 0x80000000u) ? ~u : (u | 0x80000000u);
}
__device__ __forceinline__ float unmapf(unsigned k) {
    return (k & 0x80000000u) ? __uint_as_float(k ^ 0x80000000u)
                             : __uint_as_float(~k);
}

// stage chunk C into padded LDS planes: x,y,z,ps (ALL 1024 threads).
// point p = t*4 .. t*4+3; padded addr = p + (p>>8)*4 = t*4 + (t>>6)*4
// (group of 4 never straddles a 256-block => contiguous, 16B aligned).
#define STAGE(C)                                                            \
    do {                                                                    \
        int base_ = (C)*CHUNK + t * 4;                                      \
        int pad_ = t * 4 + (t >> 6) * 4;                                    \
        float4 x4_ = *(const float4*)(pcb + base_);                         \
        float4 y4_ = *(const float4*)(pcb + NN + base_);                    \
        float4 z4_ = *(const float4*)(pcb + 2 * NN + base_);                \
        *(float4*)(s_pts + pad_) = x4_;                                     \
        *(float4*)(s_pts + PCH + pad_) = y4_;                               \
        *(float4*)(s_pts + 2 * PCH + pad_) = z4_;                           \
        float4 p4_;                                                         \
        p4_.x = fmaf(x4_.x, x4_.x, fmaf(y4_.x, y4_.x, z4_.x * z4_.x));      \
        p4_.y = fmaf(x4_.y, x4_.y, fmaf(y4_.y, y4_.y, z4_.y * z4_.y));      \
        p4_.z = fmaf(x4_.z, x4_.z, fmaf(y4_.z, y4_.z, z4_.z * z4_.z));      \
        p4_.w = fmaf(x4_.w, x4_.w, fmaf(y4_.w, y4_.w, z4_.w * z4_.w));      \
        *(float4*)(s_pts + 3 * PCH + pad_) = p4_;                           \
    } while (0)

// identical val expression in both passes (explicit fmaf => bit-deterministic)
#define VAL(X, Y, Z, PS, QX, QY, QZ) \
    fmaf((X), (QX), fmaf((Y), (QY), fmaf((Z), (QZ), (PS))))

#define PUSH(WQ, V, I)                                          \
    do {                                                        \
        int pos_ = atomicAdd(&s_cnt[WQ], 1);                    \
        if (pos_ < SCAP) {                                      \
            s_surv[((WQ)*SCAP + pos_) * 2] = (V);               \
            s_surv[((WQ)*SCAP + pos_) * 2 + 1] = __int_as_float(I); \
        }                                                       \
    } while (0)

__global__ __launch_bounds__(NTHR, 8) void soft_proj_kernel(
    const float* __restrict__ pc, const float* __restrict__ qc,
    const float* __restrict__ pf, const float* __restrict__ pfT,
    const float* __restrict__ temp, float* __restrict__ out, int useT) {
    __shared__ __align__(16) float s_pts[4 * PCH];          // 66560 B
    __shared__ __align__(16) float s_surv[QPB * SCAP * 2];  // 13824 B (val,idx)
    __shared__ int s_cnt[QPB];                              // 128 B
    __shared__ float s_thr[2 * QPB];                        // 256 B => 80768 B
    int* s_sel = (int*)s_pts;  // [QPB*KK] aliases s_pts (dead after pass B)

    const int bid = blockIdx.x;
    const int b = bid >> 7;               // 128 blocks per batch
    const int m0 = (bid & 127) * QPB;
    const int t = threadIdx.x;
    const int wave = t >> 6;              // 16 waves
    const int lane = t & 63;
    const int pairIdx = wave & 7;         // 8 wave-pairs x QPW=4 queries = 32
    const int half = wave >> 3;           // which point-half this wave scans

    const float* pcb = pc + (size_t)b * 3 * NN;
    const float* qcb = qc + (size_t)b * 3 * MM;

    // scan-phase query constants: -2*q
    float qx2[QPW], qy2[QPW], qz2[QPW];
#pragma unroll
    for (int q = 0; q < QPW; ++q) {
        int m = m0 + pairIdx * QPW + q;
        qx2[q] = -2.0f * qcb[m];
        qy2[q] = -2.0f * qcb[MM + m];
        qz2[q] = -2.0f * qcb[2 * MM + m];
    }

    float mnA[QPW], mnB[QPW];
#pragma unroll
    for (int q = 0; q < QPW; ++q) { mnA[q] = 3.0e38f; mnB[q] = 3.0e38f; }

    // ---------------- pass A: per-lane min of val over 128 points -----------
    for (int c = 0; c < NCHUNK; ++c) {
        __syncthreads();
        STAGE(c);
        __syncthreads();
        const int obp = half * 2080 + lane * 4;  // padded half base
#pragma unroll
        for (int g = 0; g < 8; ++g) {
            int oo = obp + g * 260;
            float4 x4 = *(const float4*)(s_pts + oo);
            float4 y4 = *(const float4*)(s_pts + PCH + oo);
            float4 z4 = *(const float4*)(s_pts + 2 * PCH + oo);
            float4 p4 = *(const float4*)(s_pts + 3 * PCH + oo);
#pragma unroll
            for (int q = 0; q < QPW; ++q) {
                float v0 = VAL(x4.x, y4.x, z4.x, p4.x, qx2[q], qy2[q], qz2[q]);
                float v1 = VAL(x4.y, y4.y, z4.y, p4.y, qx2[q], qy2[q], qz2[q]);
                float v2 = VAL(x4.z, y4.z, z4.z, p4.z, qx2[q], qy2[q], qz2[q]);
                float v3 = VAL(x4.w, y4.w, z4.w, p4.w, qx2[q], qy2[q], qz2[q]);
                mnA[q] = min3f(v0, v1, mnA[q]);
                mnB[q] = min3f(v2, v3, mnB[q]);
            }
        }
    }
    // combined per-(lane,query) EXACT min over this lane's 64 points
    float mnq[QPW];
#pragma unroll
    for (int q = 0; q < QPW; ++q) mnq[q] = fminf(mnA[q], mnB[q]);

    // ---- per-wave radix select: 8th-smallest of 64 lane minima (per query) --
    // coarse: top 16 mapped bits; res|0xFFFF still a provable upper bound
#pragma unroll
    for (int q = 0; q < QPW; ++q) {
        unsigned key = mapf(mnq[q]);
        unsigned res = 0u;
        for (int bb = 31; bb >= 16; --bb) {
            unsigned cand = res | (1u << bb);
            unsigned long long bal = __ballot(key < cand);
            int c2 = __popcll(bal);
            if (c2 < 8) res = cand;  // 8th smallest has this bit set
        }
        if (lane == 0)
            s_thr[half * QPB + pairIdx * QPW + q] = unmapf(res | 0xFFFFu);
    }
    if (t < QPB) s_cnt[t] = 0;
    __syncthreads();
    // t = max(tA8, tB8): >=8 points <= t in each half => >=16 total => valid
    // upper bound on the true 16th-smallest val.
    float thv[QPW];
#pragma unroll
    for (int q = 0; q < QPW; ++q)
        thv[q] = fmaxf(s_thr[pairIdx * QPW + q], s_thr[QPB + pairIdx * QPW + q]);

    // live-lane masks (wave-uniform): mnq[q] <= t => lane's set MAY contain
    // survivors; mnq[q] > t => provably none (exact skip, same VAL chain).
    unsigned long long umq[QPW];
#pragma unroll
    for (int q = 0; q < QPW; ++q) umq[q] = __ballot(mnq[q] <= thv[q]);

    // ------ pass B (sparse): rescan only live (lane,query) point-sets -------
    for (int c = 0; c < NCHUNK; ++c) {
        __syncthreads();
        STAGE(c);
        __syncthreads();
#pragma unroll
        for (int q = 0; q < QPW; ++q) {
            unsigned long long um = umq[q];
            while (um) {
                // extract up to 8 item source-lanes (uniform => SALU)
                unsigned long long u = um;
                int L0 = __ffsll(u) - 1; u &= u - 1;
                int L1 = __ffsll(u) - 1; u &= u - 1;
                int L2 = __ffsll(u) - 1; u &= u - 1;
                int L3 = __ffsll(u) - 1; u &= u - 1;
                int L4 = __ffsll(u) - 1; u &= u - 1;
                int L5 = __ffsll(u) - 1; u &= u - 1;
                int L6 = __ffsll(u) - 1; u &= u - 1;
                int L7 = __ffsll(u) - 1; u &= u - 1;
                int np = __popcll(um);
                if (np > 8) np = 8;
                um = u;
                int myit = lane >> 3;
                int La = (myit & 2) ? ((myit & 1) ? L3 : L2)
                                    : ((myit & 1) ? L1 : L0);
                int Lb = (myit & 2) ? ((myit & 1) ? L7 : L6)
                                    : ((myit & 1) ? L5 : L4);
                int L = (myit & 4) ? Lb : La;
                bool act = myit < np;
                L = act ? L : 0;
                int g = lane & 7;
                int ap = half * 2080 + L * 4 + g * 260;  // padded LDS idx
                float4 x4 = *(const float4*)(s_pts + ap);
                float4 y4 = *(const float4*)(s_pts + PCH + ap);
                float4 z4 = *(const float4*)(s_pts + 2 * PCH + ap);
                float4 p4 = *(const float4*)(s_pts + 3 * PCH + ap);
                float v0 = VAL(x4.x, y4.x, z4.x, p4.x, qx2[q], qy2[q], qz2[q]);
                float v1 = VAL(x4.y, y4.y, z4.y, p4.y, qx2[q], qy2[q], qz2[q]);
                float v2 = VAL(x4.z, y4.z, z4.z, p4.z, qx2[q], qy2[q], qz2[q]);
                float v3 = VAL(x4.w, y4.w, z4.w, p4.w, qx2[q], qy2[q], qz2[q]);
                // exact whole-group skip: min > t => every element > t
                if (act && fminf(min3f(v0, v1, v2), v3) <= thv[q]) {
                    int gi = c * CHUNK + half * 2048 + L * 4 + g * 256;
                    int wqq = pairIdx * QPW + q;
                    if (v0 <= thv[q]) PUSH(wqq, v0, gi + 0);
                    if (v1 <= thv[q]) PUSH(wqq, v1, gi + 1);
                    if (v2 <= thv[q]) PUSH(wqq, v2, gi + 2);
                    if (v3 <= thv[q]) PUSH(wqq, v3, gi + 3);
                }
            }
        }
    }
    __syncthreads();  // s_pts dead from here; s_sel (alias) becomes live

    // ------------- exact select: rank survivors by (val, idx) ---------------
#pragma unroll
    for (int qq = 0; qq < 2; ++qq) {
        int wq = wave * 2 + qq;           // 16 waves x 2 = 32 queries
        int cnt = s_cnt[wq];
        cnt = __builtin_amdgcn_readfirstlane(cnt);
        if (cnt > SCAP) cnt = SCAP;
        bool valid = lane < cnt;
        float mv = 0.f;
        int mi = 0;
        if (valid) {
            mv = s_surv[(wq * SCAP + lane) * 2];
            mi = __float_as_int(s_surv[(wq * SCAP + lane) * 2 + 1]);
        }
        int rank = 0;
        for (int j = 0; j < cnt; ++j) {
            float vj = s_surv[(wq * SCAP + j) * 2];
            int ij = __float_as_int(s_surv[(wq * SCAP + j) * 2 + 1]);
            if (valid && (vj < mv || (vj == mv && ij < mi))) rank++;
        }
        if (valid && rank < KK) s_sel[wq * KK + rank] = mi;
    }
    __syncthreads();  // survivors dead; s_surv becomes the output stage

    // -------- softmax + gather, wave-parallel: lane k owns neighbor k -------
    float* stage = s_surv;  // [67 rows][STG=33 cols]
    float tval = temp[0];
    float sigma = fmaxf(tval * tval, 1.0e-4f);
    float inv_sigma = 1.0f / sigma;
    const float* pfTb = pfT + (size_t)b * NN * FF;
    const float* pfb = pf + (size_t)b * FF * NN;

#pragma unroll
    for (int qq = 0; qq < 2; ++qq) {
        int wq = wave * 2 + qq;
        int m = m0 + wq;
        float qxe = qcb[m], qye = qcb[MM + m], qze = qcb[2 * MM + m];
        // every 16-lane group loads the same 16 neighbors (lane&15)
        int ik = s_sel[wq * KK + (lane & 15)];
        float px = pcb[ik], py = pcb[NN + ik], pz = pcb[2 * NN + ik];
        float dx = px - qxe, dy = py - qye, dz = pz - qze;
        float dk = fmaf(dx, dx, fmaf(dy, dy, dz * dz));  // exact direct form
        float dmin = dk;
#pragma unroll
        for (int s = 1; s < 16; s <<= 1) dmin = fminf(dmin, __shfl_xor(dmin, s));
        float e = __expf((dmin - dk) * inv_sigma);
        float ssum = e;
#pragma unroll
        for (int s = 1; s < 16; s <<= 1) ssum += __shfl_xor(ssum, s);
        float w = e * (1.0f / ssum);
        float sx = w * px, sy = w * py, sz = w * pz;
#pragma unroll
        for (int s = 1; s < 16; s <<= 1) {
            sx += __shfl_xor(sx, s);
            sy += __shfl_xor(sy, s);
            sz += __shfl_xor(sz, s);
        }
        // features: all 64 lanes, f = lane; weights broadcast from lanes 0-15
        float facc = 0.f;
#pragma unroll
        for (int k = 0; k < KK; ++k) {
            float wk = __shfl(w, k);
            int iik = __shfl(ik, k);
            float fv = useT ? pfTb[(size_t)iik * FF + lane]
                            : pfb[(size_t)lane * NN + iik];
            facc = fmaf(wk, fv, facc);
        }
        stage[lane * STG + wq] = facc;
        if (lane == 0) {
            stage[(64) * STG + wq] = sx;
            stage[(65) * STG + wq] = sy;
            stage[(66) * STG + wq] = sz;
        }
    }
    __syncthreads();

    // ---------------- coalesced write-out -----------------------------------
    const size_t featOff = (size_t)BB * 3 * MM;
    for (int j = t; j < 67 * QPB; j += NTHR) {
        int row = j >> 5, col = j & 31;
        float v = stage[row * STG + col];
        int m = m0 + col;
        if (row < 64)
            out[featOff + (size_t)b * FF * MM + (size_t)row * MM + m] = v;
        else
            out[(size_t)b * 3 * MM + (size_t)(row - 64) * MM + m] = v;
    }
}

extern "C" void kernel_launch(void* const* d_in, const int* in_sizes, int n_in,
                              void* d_out, int out_size, void* d_ws, size_t ws_size,
                              hipStream_t stream) {
    (void)in_sizes; (void)n_in; (void)out_size;
    const float* pc = (const float*)d_in[0];
    const float* qc = (const float*)d_in[1];
    const float* pf = (const float*)d_in[2];
    const float* temp = (const float*)d_in[3];
    float* out = (float*)d_out;
    float* pfT = (float*)d_ws;
    const size_t needT = (size_t)BB * NN * FF * sizeof(float);  // 8 MB
    int useT = (ws_size >= needT && d_ws != nullptr) ? 1 : 0;

    if (useT) {
        hipLaunchKernelGGL(transpose_feat, dim3(NN / 64, BB), dim3(256), 0, stream,
                           pf, pfT);
    }
    hipLaunchKernelGGL(soft_proj_kernel, dim3((BB * MM) / QPB), dim3(NTHR), 0,
                       stream, pc, qc, pf, pfT, temp, out, useT);
}

// Round 14
// 119.244 us; speedup vs baseline: 1.0124x; 1.0124x over previous
//
#include <hip/hip_runtime.h>

// SoftProjection: B=4, N=8192 points, M=4096 queries, F=64 features, K=16 NN.
// R16: 4 blocks/CU. Evidence R3-R15: the ONLY lever that ever moved time was
// block-decoupling (R3: 1->2 blocks/CU, -15%); instruction trims, staging
// variants, sparsity all neutral; R15 showed VALUBusy 58-75% with time
// pinned at ~57us => not purely VALU-bound; residual is inter-wave coupling.
// R16 re-parameterizes validated R11: QPB 32->16, NTHR 1024->512 => 1024
// blocks, 4 blocks/CU x 8 waves (same 32-wave cap, same 64 queries/CU) but
// 4 independent barrier groups, half the waves per sync. Proofs unchanged:
// pairIdx=wave&3, half=wave>>2; same per-lane 64-pt disjoint sets, same
// 16-iter radix 8th-per-half, t=max(halves) => >=16 pts <= t; dense pass B
// half-split, SCAP 54->52 (lambda~20, overflow P~1e-9) to fit LDS 40704B
// x4 = 162816 <= 163840. launch_bounds(512,8) => 4 blocks/CU.
// Epilogue wave-parallel exact direct-form d2 (validated R11).

#define BB 4
#define NN 8192
#define MM 4096
#define FF 64
#define KK 16
#define CHUNK 2048
#define NCHUNK 4
#define QPW 4
#define QPB 16
#define SCAP 52
#define NTHR 512
#define STG 17

__device__ __forceinline__ float min3f(float a, float b, float c) {
    float d;
    asm("v_min3_f32 %0, %1, %2, %3" : "=v"(d) : "v"(a), "v"(b), "v"(c));
    return d;
}

__global__ __launch_bounds__(256) void transpose_feat(const float* __restrict__ pf,
                                                      float* __restrict__ pfT) {
    __shared__ float tile[64][65];
    const int b = blockIdx.y;
    const int n0 = blockIdx.x * 64;
    const int t = threadIdx.x;
    const int n = t & 63, fq = t >> 6;
#pragma unroll
    for (int i = 0; i < 16; ++i) {
        int f = fq * 16 + i;
        tile[f][n] = pf[(size_t)b * FF * NN + (size_t)f * NN + n0 + n];
    }
    __syncthreads();
    const int f2 = t & 63, nq = t >> 6;
#pragma unroll
    for (int i = 0; i < 16; ++i) {
        int nn2 = nq * 16 + i;
        pfT[(size_t)b * NN * FF + (size_t)(n0 + nn2) * FF + f2] = tile[f2][nn2];
    }
}

__device__ __forceinline__ unsigned mapf(float f) {
    unsigned u = __float_as_uint(f);
    return (u & 0x80000000u) ? ~u : (u | 0x80000000u);
}
__device__ __forceinline__ float unmapf(unsigned k) {
    return (k & 0x80000000u) ? __uint_as_float(k ^ 0x80000000u)
                             : __uint_as_float(~k);
}

// stage chunk C of point cloud into LDS: x, y, z, ps=|p|^2 (ALL 512 threads)
#define STAGE(C)                                                            \
    do {                                                                    \
        int base_ = (C)*CHUNK + t * 4;                                      \
        float4 x4_ = *(const float4*)(pcb + base_);                         \
        float4 y4_ = *(const float4*)(pcb + NN + base_);                    \
        float4 z4_ = *(const float4*)(pcb + 2 * NN + base_);                \
        *(float4*)(s_pts + t * 4) = x4_;                                    \
        *(float4*)(s_pts + CHUNK + t * 4) = y4_;                            \
        *(float4*)(s_pts + 2 * CHUNK + t * 4) = z4_;                        \
        float4 p4_;                                                         \
        p4_.x = fmaf(x4_.x, x4_.x, fmaf(y4_.x, y4_.x, z4_.x * z4_.x));      \
        p4_.y = fmaf(x4_.y, x4_.y, fmaf(y4_.y, y4_.y, z4_.y * z4_.y));      \
        p4_.z = fmaf(x4_.z, x4_.z, fmaf(y4_.z, y4_.z, z4_.z * z4_.z));      \
        p4_.w = fmaf(x4_.w, x4_.w, fmaf(y4_.w, y4_.w, z4_.w * z4_.w));      \
        *(float4*)(s_pts + 3 * CHUNK + t * 4) = p4_;                        \
    } while (0)

// identical val expression in both passes (explicit fmaf => bit-deterministic)
#define VAL(X, Y, Z, PS, QX, QY, QZ) \
    fmaf((X), (QX), fmaf((Y), (QY), fmaf((Z), (QZ), (PS))))

#define PUSH(WQ, V, I)                                          \
    do {                                                        \
        int pos_ = atomicAdd(&s_cnt[WQ], 1);                    \
        if (pos_ < SCAP) {                                      \
            s_surv[((WQ)*SCAP + pos_) * 2] = (V);               \
            s_surv[((WQ)*SCAP + pos_) * 2 + 1] = __int_as_float(I); \
        }                                                       \
    } while (0)

__global__ __launch_bounds__(NTHR, 8) void soft_proj_kernel(
    const float* __restrict__ pc, const float* __restrict__ qc,
    const float* __restrict__ pf, const float* __restrict__ pfT,
    const float* __restrict__ temp, float* __restrict__ out, int useT) {
    __shared__ __align__(16) float s_pts[4 * CHUNK];        // 32768 B
    __shared__ __align__(16) float s_surv[QPB * SCAP * 2];  // 6656 B (val,idx)
    __shared__ int s_cnt[QPB];                              // 64 B
    __shared__ int s_sel[QPB * KK];                         // 1024 B
    __shared__ float s_thr[2 * QPB];                        // 128 B => 40640 B

    const int bid = blockIdx.x;
    const int b = bid >> 8;               // 256 blocks per batch
    const int m0 = (bid & 255) * QPB;
    const int t = threadIdx.x;
    const int wave = t >> 6;              // 8 waves
    const int lane = t & 63;
    const int pairIdx = wave & 3;         // 4 wave-pairs x QPW=4 queries = 16
    const int half = wave >> 2;           // which point-half this wave scans

    const float* pcb = pc + (size_t)b * 3 * NN;
    const float* qcb = qc + (size_t)b * 3 * MM;

    // scan-phase query constants: -2*q
    float qx2[QPW], qy2[QPW], qz2[QPW];
#pragma unroll
    for (int q = 0; q < QPW; ++q) {
        int m = m0 + pairIdx * QPW + q;
        qx2[q] = -2.0f * qcb[m];
        qy2[q] = -2.0f * qcb[MM + m];
        qz2[q] = -2.0f * qcb[2 * MM + m];
    }

    float mnA[QPW], mnB[QPW];
#pragma unroll
    for (int q = 0; q < QPW; ++q) { mnA[q] = 3.0e38f; mnB[q] = 3.0e38f; }

    // ---------------- pass A: per-lane min of val over 64 points ------------
    for (int c = 0; c < NCHUNK; ++c) {
        __syncthreads();
        STAGE(c);
        __syncthreads();
        const int ob = half * 1024 + lane * 4;
#pragma unroll
        for (int g = 0; g < 4; ++g) {
            int oo = ob + g * 256;
            float4 x4 = *(const float4*)(s_pts + oo);
            float4 y4 = *(const float4*)(s_pts + CHUNK + oo);
            float4 z4 = *(const float4*)(s_pts + 2 * CHUNK + oo);
            float4 p4 = *(const float4*)(s_pts + 3 * CHUNK + oo);
#pragma unroll
            for (int q = 0; q < QPW; ++q) {
                float v0 = VAL(x4.x, y4.x, z4.x, p4.x, qx2[q], qy2[q], qz2[q]);
                float v1 = VAL(x4.y, y4.y, z4.y, p4.y, qx2[q], qy2[q], qz2[q]);
                float v2 = VAL(x4.z, y4.z, z4.z, p4.z, qx2[q], qy2[q], qz2[q]);
                float v3 = VAL(x4.w, y4.w, z4.w, p4.w, qx2[q], qy2[q], qz2[q]);
                mnA[q] = min3f(v0, v1, mnA[q]);
                mnB[q] = min3f(v2, v3, mnB[q]);
            }
        }
    }

    // ---- per-wave radix select: 8th-smallest of 64 lane minima (per query) --
    // coarse: top 16 mapped bits; res|0xFFFF still a provable upper bound
#pragma unroll
    for (int q = 0; q < QPW; ++q) {
        unsigned key = mapf(fminf(mnA[q], mnB[q]));
        unsigned res = 0u;
        for (int bb = 31; bb >= 16; --bb) {
            unsigned cand = res | (1u << bb);
            unsigned long long bal = __ballot(key < cand);
            int c2 = __popcll(bal);
            if (c2 < 8) res = cand;  // 8th smallest has this bit set
        }
        if (lane == 0)
            s_thr[half * QPB + pairIdx * QPW + q] = unmapf(res | 0xFFFFu);
    }
    if (t < QPB) s_cnt[t] = 0;
    __syncthreads();
    // t = max(tA8, tB8): >=8 points <= t in each half => >=16 total => valid
    // upper bound on the true 16th-smallest val.
    float thv[QPW];
#pragma unroll
    for (int q = 0; q < QPW; ++q)
        thv[q] = fmaxf(s_thr[pairIdx * QPW + q], s_thr[QPB + pairIdx * QPW + q]);

    // ---------------- pass B: collect survivors val <= t --------------------
    for (int c = 0; c < NCHUNK; ++c) {
        __syncthreads();
        STAGE(c);
        __syncthreads();
        const int ob = half * 1024 + lane * 4;
#pragma unroll
        for (int g = 0; g < 4; ++g) {
            int oo = ob + g * 256;
            float4 x4 = *(const float4*)(s_pts + oo);
            float4 y4 = *(const float4*)(s_pts + CHUNK + oo);
            float4 z4 = *(const float4*)(s_pts + 2 * CHUNK + oo);
            float4 p4 = *(const float4*)(s_pts + 3 * CHUNK + oo);
            int gi = c * CHUNK + oo;
#pragma unroll
            for (int q = 0; q < QPW; ++q) {
                float v0 = VAL(x4.x, y4.x, z4.x, p4.x, qx2[q], qy2[q], qz2[q]);
                float v1 = VAL(x4.y, y4.y, z4.y, p4.y, qx2[q], qy2[q], qz2[q]);
                float v2 = VAL(x4.z, y4.z, z4.z, p4.z, qx2[q], qy2[q], qz2[q]);
                float v3 = VAL(x4.w, y4.w, z4.w, p4.w, qx2[q], qy2[q], qz2[q]);
                // exact whole-group skip: min > t => every element > t
                if (fminf(min3f(v0, v1, v2), v3) <= thv[q]) {
                    int wqq = pairIdx * QPW + q;
                    if (v0 <= thv[q]) PUSH(wqq, v0, gi + 0);
                    if (v1 <= thv[q]) PUSH(wqq, v1, gi + 1);
                    if (v2 <= thv[q]) PUSH(wqq, v2, gi + 2);
                    if (v3 <= thv[q]) PUSH(wqq, v3, gi + 3);
                }
            }
        }
    }
    __syncthreads();

    // ------------- exact select: rank survivors by (val, idx) ---------------
#pragma unroll
    for (int qq = 0; qq < 2; ++qq) {
        int wq = wave * 2 + qq;           // 8 waves x 2 = 16 queries
        int cnt = s_cnt[wq];
        cnt = __builtin_amdgcn_readfirstlane(cnt);
        if (cnt > SCAP) cnt = SCAP;
        bool valid = lane < cnt;
        float mv = 0.f;
        int mi = 0;
        if (valid) {
            mv = s_surv[(wq * SCAP + lane) * 2];
            mi = __float_as_int(s_surv[(wq * SCAP + lane) * 2 + 1]);
        }
        int rank = 0;
        for (int j = 0; j < cnt; ++j) {
            float vj = s_surv[(wq * SCAP + j) * 2];
            int ij = __float_as_int(s_surv[(wq * SCAP + j) * 2 + 1]);
            if (valid && (vj < mv || (vj == mv && ij < mi))) rank++;
        }
        if (valid && rank < KK) s_sel[wq * KK + rank] = mi;
    }
    __syncthreads();  // survivors dead; s_surv becomes the output stage

    // -------- softmax + gather, wave-parallel: lane k owns neighbor k -------
    float* stage = s_surv;  // [67 rows][STG=17 cols]
    float tval = temp[0];
    float sigma = fmaxf(tval * tval, 1.0e-4f);
    float inv_sigma = 1.0f / sigma;
    const float* pfTb = pfT + (size_t)b * NN * FF;
    const float* pfb = pf + (size_t)b * FF * NN;

#pragma unroll
    for (int qq = 0; qq < 2; ++qq) {
        int wq = wave * 2 + qq;
        int m = m0 + wq;
        float qxe = qcb[m], qye = qcb[MM + m], qze = qcb[2 * MM + m];
        // every 16-lane group loads the same 16 neighbors (lane&15)
        int ik = s_sel[wq * KK + (lane & 15)];
        float px = pcb[ik], py = pcb[NN + ik], pz = pcb[2 * NN + ik];
        float dx = px - qxe, dy = py - qye, dz = pz - qze;
        float dk = fmaf(dx, dx, fmaf(dy, dy, dz * dz));  // exact direct form
        float dmin = dk;
#pragma unroll
        for (int s = 1; s < 16; s <<= 1) dmin = fminf(dmin, __shfl_xor(dmin, s));
        float e = __expf((dmin - dk) * inv_sigma);
        float ssum = e;
#pragma unroll
        for (int s = 1; s < 16; s <<= 1) ssum += __shfl_xor(ssum, s);
        float w = e * (1.0f / ssum);
        float sx = w * px, sy = w * py, sz = w * pz;
#pragma unroll
        for (int s = 1; s < 16; s <<= 1) {
            sx += __shfl_xor(sx, s);
            sy += __shfl_xor(sy, s);
            sz += __shfl_xor(sz, s);
        }
        // features: all 64 lanes, f = lane; weights broadcast from lanes 0-15
        float facc = 0.f;
#pragma unroll
        for (int k = 0; k < KK; ++k) {
            float wk = __shfl(w, k);
            int iik = __shfl(ik, k);
            float fv = useT ? pfTb[(size_t)iik * FF + lane]
                            : pfb[(size_t)lane * NN + iik];
            facc = fmaf(wk, fv, facc);
        }
        stage[lane * STG + wq] = facc;
        if (lane == 0) {
            stage[(64) * STG + wq] = sx;
            stage[(65) * STG + wq] = sy;
            stage[(66) * STG + wq] = sz;
        }
    }
    __syncthreads();

    // ---------------- coalesced write-out -----------------------------------
    const size_t featOff = (size_t)BB * 3 * MM;
    for (int j = t; j < 67 * QPB; j += NTHR) {
        int row = j >> 4, col = j & 15;
        float v = stage[row * STG + col];
        int m = m0 + col;
        if (row < 64)
            out[featOff + (size_t)b * FF * MM + (size_t)row * MM + m] = v;
        else
            out[(size_t)b * 3 * MM + (size_t)(row - 64) * MM + m] = v;
    }
}

extern "C" void kernel_launch(void* const* d_in, const int* in_sizes, int n_in,
                              void* d_out, int out_size, void* d_ws, size_t ws_size,
                              hipStream_t stream) {
    (void)in_sizes; (void)n_in; (void)out_size;
    const float* pc = (const float*)d_in[0];
    const float* qc = (const float*)d_in[1];
    const float* pf = (const float*)d_in[2];
    const float* temp = (const float*)d_in[3];
    float* out = (float*)d_out;
    float* pfT = (float*)d_ws;
    const size_t needT = (size_t)BB * NN * FF * sizeof(float);  // 8 MB
    int useT = (ws_size >= needT && d_ws != nullptr) ? 1 : 0;

    if (useT) {
        hipLaunchKernelGGL(transpose_feat, dim3(NN / 64, BB), dim3(256), 0, stream,
                           pf, pfT);
    }
    hipLaunchKernelGGL(soft_proj_kernel, dim3((BB * MM) / QPB), dim3(NTHR), 0,
                       stream, pc, qc, pf, pfT, temp, out, useT);
}

// Round 15
// 118.005 us; speedup vs baseline: 1.0230x; 1.0105x over previous
//
#include <hip/hip_runtime.h>

// SoftProjection: B=4, N=8192 points, M=4096 queries, F=64 features, K=16 NN.
// R17 (FINAL): revert to R11, the session's verified best (118.9us total /
// 57.2us main). R16 (4 blocks/CU) regressed ~5% (per-CU staging doubled).
// Session ledger -- real wins: R3 occupancy decouple (1->2 blocks/CU, -15%),
// R11 min3 trims + wave-parallel epilogue (-2%). Falsified levers: packed
// fp32 (spill), async DMA staging, L2-direct scan, pass-B query-sharing x2
// (regalloc spill), big-chunk staging, sparse rescan (bank conflicts),
// finer barrier groups. MFMA filter failed correctness structurally (3
// rounds). Time pinned ~57us across VALUBusy 58-75% / occupancy 42-75% /
// HBM 6% => empirical floor of the exact-KNN scan structure: mixed
// VALU-issue + LDS-port + dependency, no counter >80% to push against.
//
// Structure: QPB=32, QPW=4 wave-pairs, 512 blocks x 1024 thr, LDS 49KB =>
// 2 blocks/CU. Pass A: val = |p|^2 - 2 q.p per-lane min (min3 split);
// per-wave 16-iter radix/ballot 8th-smallest per point-half; t=max(halves)
// => provable upper bound on true 16th NN. Pass B: survivors val<=t
// (min3 whole-group skip, E~20, cap 54); exact rank by (val,idx).
// Epilogue: wave-parallel lane-k-owns-neighbor-k, exact direct-form d2
// softmax (matches reference), shfl_xor tree reductions.

#define BB 4
#define NN 8192
#define MM 4096
#define FF 64
#define KK 16
#define CHUNK 2048
#define NCHUNK 4
#define QPW 4
#define QPB 32
#define SCAP 54
#define NTHR 1024
#define STG 33

__device__ __forceinline__ float min3f(float a, float b, float c) {
    float d;
    asm("v_min3_f32 %0, %1, %2, %3" : "=v"(d) : "v"(a), "v"(b), "v"(c));
    return d;
}

__global__ __launch_bounds__(256) void transpose_feat(const float* __restrict__ pf,
                                                      float* __restrict__ pfT) {
    __shared__ float tile[64][65];
    const int b = blockIdx.y;
    const int n0 = blockIdx.x * 64;
    const int t = threadIdx.x;
    const int n = t & 63, fq = t >> 6;
#pragma unroll
    for (int i = 0; i < 16; ++i) {
        int f = fq * 16 + i;
        tile[f][n] = pf[(size_t)b * FF * NN + (size_t)f * NN + n0 + n];
    }
    __syncthreads();
    const int f2 = t & 63, nq = t >> 6;
#pragma unroll
    for (int i = 0; i < 16; ++i) {
        int nn2 = nq * 16 + i;
        pfT[(size_t)b * NN * FF + (size_t)(n0 + nn2) * FF + f2] = tile[f2][nn2];
    }
}

__device__ __forceinline__ unsigned mapf(float f) {
    unsigned u = __float_as_uint(f);
    return (u & 0x80000000u) ? ~u : (u | 0x80000000u);
}
__device__ __forceinline__ float unmapf(unsigned k) {
    return (k & 0x80000000u) ? __uint_as_float(k ^ 0x80000000u)
                             : __uint_as_float(~k);
}

// stage chunk C of point cloud into LDS: x, y, z, ps=|p|^2 (512 stager threads)
#define STAGE(C)                                                            \
    do {                                                                    \
        if (t < CHUNK / 4) {                                                \
            int base_ = (C)*CHUNK + t * 4;                                  \
            float4 x4_ = *(const float4*)(pcb + base_);                     \
            float4 y4_ = *(const float4*)(pcb + NN + base_);                \
            float4 z4_ = *(const float4*)(pcb + 2 * NN + base_);            \
            *(float4*)(s_pts + t * 4) = x4_;                                \
            *(float4*)(s_pts + CHUNK + t * 4) = y4_;                        \
            *(float4*)(s_pts + 2 * CHUNK + t * 4) = z4_;                    \
            float4 p4_;                                                     \
            p4_.x = fmaf(x4_.x, x4_.x, fmaf(y4_.x, y4_.x, z4_.x * z4_.x));  \
            p4_.y = fmaf(x4_.y, x4_.y, fmaf(y4_.y, y4_.y, z4_.y * z4_.y));  \
            p4_.z = fmaf(x4_.z, x4_.z, fmaf(y4_.z, y4_.z, z4_.z * z4_.z));  \
            p4_.w = fmaf(x4_.w, x4_.w, fmaf(y4_.w, y4_.w, z4_.w * z4_.w));  \
            *(float4*)(s_pts + 3 * CHUNK + t * 4) = p4_;                    \
        }                                                                   \
    } while (0)

// identical val expression in both passes (explicit fmaf => bit-deterministic)
#define VAL(X, Y, Z, PS, QX, QY, QZ) \
    fmaf((X), (QX), fmaf((Y), (QY), fmaf((Z), (QZ), (PS))))

#define PUSH(WQ, V, I)                                          \
    do {                                                        \
        int pos_ = atomicAdd(&s_cnt[WQ], 1);                    \
        if (pos_ < SCAP) {                                      \
            s_surv[((WQ)*SCAP + pos_) * 2] = (V);               \
            s_surv[((WQ)*SCAP + pos_) * 2 + 1] = __int_as_float(I); \
        }                                                       \
    } while (0)

__global__ __launch_bounds__(NTHR, 8) void soft_proj_kernel(
    const float* __restrict__ pc, const float* __restrict__ qc,
    const float* __restrict__ pf, const float* __restrict__ pfT,
    const float* __restrict__ temp, float* __restrict__ out, int useT) {
    __shared__ __align__(16) float s_pts[4 * CHUNK];        // 32768 B
    __shared__ __align__(16) float s_surv[QPB * SCAP * 2];  // 13824 B (val,idx)
    __shared__ int s_cnt[QPB];                              // 128 B
    __shared__ int s_sel[QPB * KK];                         // 2048 B
    __shared__ float s_thr[2 * QPB];                        // 256 B => 49024 B

    const int bid = blockIdx.x;
    const int b = bid >> 7;               // 128 blocks per batch
    const int m0 = (bid & 127) * QPB;
    const int t = threadIdx.x;
    const int wave = t >> 6;              // 16 waves
    const int lane = t & 63;
    const int pairIdx = wave & 7;         // 8 wave-pairs x QPW=4 queries = 32
    const int half = wave >> 3;           // which point-half this wave scans

    const float* pcb = pc + (size_t)b * 3 * NN;
    const float* qcb = qc + (size_t)b * 3 * MM;

    // scan-phase query constants: -2*q
    float qx2[QPW], qy2[QPW], qz2[QPW];
#pragma unroll
    for (int q = 0; q < QPW; ++q) {
        int m = m0 + pairIdx * QPW + q;
        qx2[q] = -2.0f * qcb[m];
        qy2[q] = -2.0f * qcb[MM + m];
        qz2[q] = -2.0f * qcb[2 * MM + m];
    }

    float mnA[QPW], mnB[QPW];
#pragma unroll
    for (int q = 0; q < QPW; ++q) { mnA[q] = 3.0e38f; mnB[q] = 3.0e38f; }

    // ---------------- pass A: per-lane min of val over 64 points ------------
    for (int c = 0; c < NCHUNK; ++c) {
        __syncthreads();
        STAGE(c);
        __syncthreads();
        const int ob = half * 1024 + lane * 4;
#pragma unroll
        for (int g = 0; g < 4; ++g) {
            int oo = ob + g * 256;
            float4 x4 = *(const float4*)(s_pts + oo);
            float4 y4 = *(const float4*)(s_pts + CHUNK + oo);
            float4 z4 = *(const float4*)(s_pts + 2 * CHUNK + oo);
            float4 p4 = *(const float4*)(s_pts + 3 * CHUNK + oo);
#pragma unroll
            for (int q = 0; q < QPW; ++q) {
                float v0 = VAL(x4.x, y4.x, z4.x, p4.x, qx2[q], qy2[q], qz2[q]);
                float v1 = VAL(x4.y, y4.y, z4.y, p4.y, qx2[q], qy2[q], qz2[q]);
                float v2 = VAL(x4.z, y4.z, z4.z, p4.z, qx2[q], qy2[q], qz2[q]);
                float v3 = VAL(x4.w, y4.w, z4.w, p4.w, qx2[q], qy2[q], qz2[q]);
                mnA[q] = min3f(v0, v1, mnA[q]);
                mnB[q] = min3f(v2, v3, mnB[q]);
            }
        }
    }

    // ---- per-wave radix select: 8th-smallest of 64 lane minima (per query) --
    // coarse: top 16 mapped bits; res|0xFFFF still a provable upper bound
#pragma unroll
    for (int q = 0; q < QPW; ++q) {
        unsigned key = mapf(fminf(mnA[q], mnB[q]));
        unsigned res = 0u;
        for (int bb = 31; bb >= 16; --bb) {
            unsigned cand = res | (1u << bb);
            unsigned long long bal = __ballot(key < cand);
            int c2 = __popcll(bal);
            if (c2 < 8) res = cand;  // 8th smallest has this bit set
        }
        if (lane == 0)
            s_thr[half * QPB + pairIdx * QPW + q] = unmapf(res | 0xFFFFu);
    }
    if (t < QPB) s_cnt[t] = 0;
    __syncthreads();
    // t = max(tA8, tB8): >=8 points <= t in each half => >=16 total => valid
    // upper bound on the true 16th-smallest val.
    float thv[QPW];
#pragma unroll
    for (int q = 0; q < QPW; ++q)
        thv[q] = fmaxf(s_thr[pairIdx * QPW + q], s_thr[QPB + pairIdx * QPW + q]);

    // ---------------- pass B: collect survivors val <= t --------------------
    for (int c = 0; c < NCHUNK; ++c) {
        __syncthreads();
        STAGE(c);
        __syncthreads();
        const int ob = half * 1024 + lane * 4;
#pragma unroll
        for (int g = 0; g < 4; ++g) {
            int oo = ob + g * 256;
            float4 x4 = *(const float4*)(s_pts + oo);
            float4 y4 = *(const float4*)(s_pts + CHUNK + oo);
            float4 z4 = *(const float4*)(s_pts + 2 * CHUNK + oo);
            float4 p4 = *(const float4*)(s_pts + 3 * CHUNK + oo);
            int gi = c * CHUNK + oo;
#pragma unroll
            for (int q = 0; q < QPW; ++q) {
                float v0 = VAL(x4.x, y4.x, z4.x, p4.x, qx2[q], qy2[q], qz2[q]);
                float v1 = VAL(x4.y, y4.y, z4.y, p4.y, qx2[q], qy2[q], qz2[q]);
                float v2 = VAL(x4.z, y4.z, z4.z, p4.z, qx2[q], qy2[q], qz2[q]);
                float v3 = VAL(x4.w, y4.w, z4.w, p4.w, qx2[q], qy2[q], qz2[q]);
                // exact whole-group skip: min > t => every element > t
                if (fminf(min3f(v0, v1, v2), v3) <= thv[q]) {
                    int wqq = pairIdx * QPW + q;
                    if (v0 <= thv[q]) PUSH(wqq, v0, gi + 0);
                    if (v1 <= thv[q]) PUSH(wqq, v1, gi + 1);
                    if (v2 <= thv[q]) PUSH(wqq, v2, gi + 2);
                    if (v3 <= thv[q]) PUSH(wqq, v3, gi + 3);
                }
            }
        }
    }
    __syncthreads();

    // ------------- exact select: rank survivors by (val, idx) ---------------
#pragma unroll
    for (int qq = 0; qq < 2; ++qq) {
        int wq = wave * 2 + qq;           // 16 waves x 2 = 32 queries
        int cnt = s_cnt[wq];
        cnt = __builtin_amdgcn_readfirstlane(cnt);
        if (cnt > SCAP) cnt = SCAP;
        bool valid = lane < cnt;
        float mv = 0.f;
        int mi = 0;
        if (valid) {
            mv = s_surv[(wq * SCAP + lane) * 2];
            mi = __float_as_int(s_surv[(wq * SCAP + lane) * 2 + 1]);
        }
        int rank = 0;
        for (int j = 0; j < cnt; ++j) {
            float vj = s_surv[(wq * SCAP + j) * 2];
            int ij = __float_as_int(s_surv[(wq * SCAP + j) * 2 + 1]);
            if (valid && (vj < mv || (vj == mv && ij < mi))) rank++;
        }
        if (valid && rank < KK) s_sel[wq * KK + rank] = mi;
    }
    __syncthreads();  // survivors dead; s_surv becomes the output stage

    // -------- softmax + gather, wave-parallel: lane k owns neighbor k -------
    float* stage = s_surv;  // [67 rows][STG=33 cols]
    float tval = temp[0];
    float sigma = fmaxf(tval * tval, 1.0e-4f);
    float inv_sigma = 1.0f / sigma;
    const float* pfTb = pfT + (size_t)b * NN * FF;
    const float* pfb = pf + (size_t)b * FF * NN;

#pragma unroll
    for (int qq = 0; qq < 2; ++qq) {
        int wq = wave * 2 + qq;
        int m = m0 + wq;
        float qxe = qcb[m], qye = qcb[MM + m], qze = qcb[2 * MM + m];
        // every 16-lane group loads the same 16 neighbors (lane&15)
        int ik = s_sel[wq * KK + (lane & 15)];
        float px = pcb[ik], py = pcb[NN + ik], pz = pcb[2 * NN + ik];
        float dx = px - qxe, dy = py - qye, dz = pz - qze;
        float dk = fmaf(dx, dx, fmaf(dy, dy, dz * dz));  // exact direct form
        float dmin = dk;
#pragma unroll
        for (int s = 1; s < 16; s <<= 1) dmin = fminf(dmin, __shfl_xor(dmin, s));
        float e = __expf((dmin - dk) * inv_sigma);
        float ssum = e;
#pragma unroll
        for (int s = 1; s < 16; s <<= 1) ssum += __shfl_xor(ssum, s);
        float w = e * (1.0f / ssum);
        float sx = w * px, sy = w * py, sz = w * pz;
#pragma unroll
        for (int s = 1; s < 16; s <<= 1) {
            sx += __shfl_xor(sx, s);
            sy += __shfl_xor(sy, s);
            sz += __shfl_xor(sz, s);
        }
        // features: all 64 lanes, f = lane; weights broadcast from lanes 0-15
        float facc = 0.f;
#pragma unroll
        for (int k = 0; k < KK; ++k) {
            float wk = __shfl(w, k);
            int iik = __shfl(ik, k);
            float fv = useT ? pfTb[(size_t)iik * FF + lane]
                            : pfb[(size_t)lane * NN + iik];
            facc = fmaf(wk, fv, facc);
        }
        stage[lane * STG + wq] = facc;
        if (lane == 0) {
            stage[(64) * STG + wq] = sx;
            stage[(65) * STG + wq] = sy;
            stage[(66) * STG + wq] = sz;
        }
    }
    __syncthreads();

    // ---------------- coalesced write-out -----------------------------------
    const size_t featOff = (size_t)BB * 3 * MM;
    for (int j = t; j < 67 * QPB; j += NTHR) {
        int row = j >> 5, col = j & 31;
        float v = stage[row * STG + col];
        int m = m0 + col;
        if (row < 64)
            out[featOff + (size_t)b * FF * MM + (size_t)row * MM + m] = v;
        else
            out[(size_t)b * 3 * MM + (size_t)(row - 64) * MM + m] = v;
    }
}

extern "C" void kernel_launch(void* const* d_in, const int* in_sizes, int n_in,
                              void* d_out, int out_size, void* d_ws, size_t ws_size,
                              hipStream_t stream) {
    (void)in_sizes; (void)n_in; (void)out_size;
    const float* pc = (const float*)d_in[0];
    const float* qc = (const float*)d_in[1];
    const float* pf = (const float*)d_in[2];
    const float* temp = (const float*)d_in[3];
    float* out = (float*)d_out;
    float* pfT = (float*)d_ws;
    const size_t needT = (size_t)BB * NN * FF * sizeof(float);  // 8 MB
    int useT = (ws_size >= needT && d_ws != nullptr) ? 1 : 0;

    if (useT) {
        hipLaunchKernelGGL(transpose_feat, dim3(NN / 64, BB), dim3(256), 0, stream,
                           pf, pfT);
    }
    hipLaunchKernelGGL(soft_proj_kernel, dim3((BB * MM) / QPB), dim3(NTHR), 0,
                       stream, pc, qc, pf, pfT, temp, out, useT);
}